// Round 7
// baseline (39.714 us; speedup 1.0000x reference)
//
#include <hip/hip_runtime.h>
#include <hip/hip_bf16.h>

// Problem constants (fixed by the reference file):
//   B=16 docs, PREV(K)=768, D(N)=256, lengths[i]=1024+128*i, T=31744, MAXLEN=2944
// Doc start offsets are multiples of 128 -> 32-row M-tiles never straddle docs.
// Per-doc padding 1920-128*d is a multiple of 64 -> 64-row zero tiles never straddle.

#define T_TOTAL 31744
#define K_DIM   768
#define N_DIM   256
#define MAXLEN  2944
#define NKT     24          // K_DIM / 32
#define NGEMM   992         // T_TOTAL / 32
#define NZERO   240         // 15360 padding rows / 64

typedef __attribute__((ext_vector_type(8))) short    bf16x8;
typedef __attribute__((ext_vector_type(4))) float    f32x4;
typedef __attribute__((ext_vector_type(4))) unsigned u32x4;

__device__ __forceinline__ unsigned short f2bf(float f) {
  unsigned u = __builtin_bit_cast(unsigned, f);
  u += 0x7fffu + ((u >> 16) & 1u);
  return (unsigned short)(u >> 16);
}

__device__ __forceinline__ unsigned cvtpk(float lo, float hi) {
  unsigned r;
  asm("v_cvt_pk_bf16_f32 %0, %1, %2" : "=v"(r) : "v"(lo), "v"(hi));
  return r;
}

// async global->LDS, 16B per lane; LDS dest = wave-uniform base + lane*16
__device__ __forceinline__ void gload16(const void* g, void* l) {
  __builtin_amdgcn_global_load_lds(
      (const __attribute__((address_space(1))) unsigned int*)g,
      (__attribute__((address_space(3))) unsigned int*)l,
      16, 0, 0);
}

// ---------------------------------------------------------------------------
// Kernel 1: W [768][256] f32 -> Wt_tiled bf16 in EXACT per-K-step LDS image
// order: element (kt, h, col, e) = bf16(W[kt*32 + h*8 + e][col]).
// GEMM staging of B is then a contiguous 16KB copy per K-step.
// ---------------------------------------------------------------------------
__global__ __launch_bounds__(256) void wt_tile(const float* __restrict__ W,
                                               unsigned short* __restrict__ Wt) {
  __shared__ float Wl[32][257];     // +1 pad
  const int kt  = blockIdx.x;       // 0..23
  const int tid = threadIdx.x;

#pragma unroll
  for (int i = 0; i < 8; ++i) {
    const int idx = i * 256 + tid;          // 0..2047 chunks of f32x4
    const int row = idx >> 6;
    const int c4  = idx & 63;
    f32x4 v = *(const f32x4*)(W + (size_t)(kt * 32 + row) * N_DIM + c4 * 4);
    Wl[row][c4 * 4 + 0] = v[0];
    Wl[row][c4 * 4 + 1] = v[1];
    Wl[row][c4 * 4 + 2] = v[2];
    Wl[row][c4 * 4 + 3] = v[3];
  }
  __syncthreads();

#pragma unroll
  for (int h = 0; h < 4; ++h) {
    bf16x8 ov;
#pragma unroll
    for (int e = 0; e < 8; ++e) ov[e] = (short)f2bf(Wl[h * 8 + e][tid]);
    *(bf16x8*)(Wt + (((size_t)kt * 4 + h) * 256 + tid) * 8) = ov;
  }
}

// ---------------------------------------------------------------------------
// Kernel 2: GEMM + scatter + fused padding zero-fill.
//   blocks [0, NGEMM):    BM=32 GEMM tile (2-phase global_load_lds pipeline)
//   blocks [NGEMM, +240): zero 64 padding rows each (write-only, overlaps)
//
// LDS (40KB/block -> 4 blocks/CU):
//   A image (4KB/buf):  slot16 = row*8 + g', g' = g ^ (row&7) (XOR swizzle);
//       staged by waves 0..3; frag read spreads 16 lanes over 8 slots (2-way).
//   B image (16KB/buf): contiguous copy from Wt_tiled; frag read conflict-free.
// 512 threads = 8 waves; wave w owns cols w*32..+31 (2x2 frags, acc 16 VGPR).
// ---------------------------------------------------------------------------
__global__ __launch_bounds__(512, 8) void gemm_scatter(const float* __restrict__ A,
                                                       const unsigned short* __restrict__ Wt,
                                                       const float* __restrict__ bias,
                                                       float* __restrict__ out) {
  const int tid = threadIdx.x;

  // ---------------- fused zero-fill blocks ----------------
  if (blockIdx.x >= NGEMM) {
    const int z  = blockIdx.x - NGEMM;   // 0..239
    const int p0 = z * 64;               // global padding-row index
    int d = 0, c = 0;
    while (d < 15) {
      const int pad = 1920 - 128 * d;
      if (p0 < c + pad) break;
      c += pad; ++d;
    }
    const int len = 1024 + 128 * d;
    const size_t row0 = (size_t)d * MAXLEN + len + (p0 - c);
    float* dst = out + row0 * N_DIM;
    const f32x4 z4 = {0.f, 0.f, 0.f, 0.f};
#pragma unroll
    for (int j = 0; j < 8; ++j)
      *(f32x4*)(dst + (size_t)(j * 512 + tid) * 4) = z4;
    return;
  }

  // ---------------- GEMM blocks ----------------
  __shared__ f32x4 AbV[2][256];    // 2 x 4KB
  __shared__ f32x4 BbV[2][1024];   // 2 x 16KB

  const int wid  = tid >> 6;
  const int lane = tid & 63;
  const int l15  = lane & 15;
  const int l4   = lane >> 4;
  const int t0   = blockIdx.x * 32;

  // which doc does this tile live in (tiles never straddle docs)
  int off = 0, doc = 0;
  while (doc < 15) {
    const int len = 1024 + 128 * doc;
    if (t0 < off + len) break;
    off += len; ++doc;
  }
  const long tgt0 = (long)doc * MAXLEN + (t0 - off);

  // ---- staging source addresses ----
  // A (waves 0..3, tid<256): slot16 = tid = row*8 + g'; g = g' ^ (row&7)
  const int rowA = (tid & 255) >> 3;
  const int gA   = (tid & 7) ^ (rowA & 7);
  const float* pA = A + (size_t)(t0 + rowA) * K_DIM + gA * 4;
  // B: contiguous from Wt_tiled; per step offset kt*8192 elements (16KB)
  const unsigned short* pB = Wt + (size_t)tid * 8;

  // ---- wave-uniform LDS staging bases ----
  char* ldsA  = (char*)&AbV[0][0];
  char* ldsB  = (char*)&BbV[0][0];
  char* ldsAw = ldsA + wid * 1024;          // only wid<4 used for A
  char* ldsBw = ldsB + wid * 1024;

  // ---- fragment read offsets ----
  const int s_a   = l15 & 7;
  const int aoff0 = l15 * 128 + (((l4 << 1)    ) ^ s_a) * 16;  // rows l15,  k=l4*8..+3
  const int aoff1 = l15 * 128 + (((l4 << 1) | 1) ^ s_a) * 16;  //            k=l4*8+4..+7
  const int boff  = l4 * 4096 + (wid * 32 + l15) * 16;

  f32x4 acc[2][2];
#pragma unroll
  for (int m = 0; m < 2; ++m)
#pragma unroll
    for (int n = 0; n < 2; ++n) acc[m][n] = f32x4{0.f, 0.f, 0.f, 0.f};

#define STAGE(buf, kt_)                                                  \
  {                                                                      \
    if (wid < 4) gload16(pA + (kt_) * 32, ldsAw + (buf) * 4096);         \
    gload16(pB + (size_t)(kt_) * 8192, ldsBw + (buf) * 16384);           \
    gload16(pB + (size_t)(kt_) * 8192 + 4096,                            \
            ldsBw + (buf) * 16384 + 8192);                               \
  }

#define COMPUTE(buf)                                                     \
  {                                                                      \
    const char* ab = ldsA + (buf) * 4096;                                \
    const char* bb = ldsB + (buf) * 16384 + boff;                        \
    bf16x8 bf0 = *(const bf16x8*)(bb);                                   \
    bf16x8 bf1 = *(const bf16x8*)(bb + 256);                             \
    _Pragma("unroll") for (int m = 0; m < 2; ++m) {                      \
      f32x4 av0 = *(const f32x4*)(ab + aoff0 + m * 2048);                \
      f32x4 av1 = *(const f32x4*)(ab + aoff1 + m * 2048);                \
      u32x4 u;                                                           \
      u[0] = cvtpk(av0[0], av0[1]); u[1] = cvtpk(av0[2], av0[3]);        \
      u[2] = cvtpk(av1[0], av1[1]); u[3] = cvtpk(av1[2], av1[3]);        \
      bf16x8 af = __builtin_bit_cast(bf16x8, u);                         \
      acc[m][0] = __builtin_amdgcn_mfma_f32_16x16x32_bf16(af, bf0, acc[m][0], 0, 0, 0); \
      acc[m][1] = __builtin_amdgcn_mfma_f32_16x16x32_bf16(af, bf1, acc[m][1], 0, 0, 0); \
    }                                                                    \
  }

  STAGE(0, 0)
  __syncthreads();

#pragma unroll 1
  for (int t = 0; t < NKT - 1; ++t) {
    STAGE((t + 1) & 1, t + 1)
    COMPUTE(t & 1)
    __syncthreads();
  }
  COMPUTE((NKT - 1) & 1)

  // epilogue: bias + scatter to padded rows
  float bc[2];
#pragma unroll
  for (int n = 0; n < 2; ++n) bc[n] = bias[wid * 32 + n * 16 + l15];

#pragma unroll
  for (int m = 0; m < 2; ++m)
#pragma unroll
    for (int n = 0; n < 2; ++n) {
      const size_t base = (size_t)(tgt0 + m * 16 + l4 * 4) * N_DIM
                        + wid * 32 + n * 16 + l15;
#pragma unroll
      for (int j = 0; j < 4; ++j)
        out[base + (size_t)j * N_DIM] = acc[m][n][j] + bc[n];
    }
#undef STAGE
#undef COMPUTE
}

// ---------------------------------------------------------------------------
extern "C" void kernel_launch(void* const* d_in, const int* in_sizes, int n_in,
                              void* d_out, int out_size, void* d_ws, size_t ws_size,
                              hipStream_t stream) {
  const float* A    = (const float*)d_in[0];   // [31744, 768]
  const float* W    = (const float*)d_in[1];   // [768, 256]
  const float* bias = (const float*)d_in[2];   // [256]
  float* out = (float*)d_out;                  // [16, 2944, 256]
  unsigned short* Wt = (unsigned short*)d_ws;  // Wt_tiled bf16 [24][4][256][8]

  wt_tile<<<24, 256, 0, stream>>>(W, Wt);
  gemm_scatter<<<NGEMM + NZERO, 512, 0, stream>>>(A, Wt, bias, out);
}

// Round 8
// 33.568 us; speedup vs baseline: 1.1831x; 1.1831x over previous
//
#include <hip/hip_runtime.h>
#include <hip/hip_bf16.h>

// Problem constants (fixed by the reference file):
//   B=16 docs, PREV(K)=768, D(N)=256, lengths[i]=1024+128*i, T=31744, MAXLEN=2944
// Doc start offsets are multiples of 128 -> 64-row M-tiles never straddle docs.
// Per-doc padding 1920-128*d is a multiple of 64 -> 64-row zero tiles never straddle.

#define T_TOTAL 31744
#define K_DIM   768
#define N_DIM   256
#define MAXLEN  2944
#define NKT     24          // K_DIM / 32
#define NGEMM   496         // T_TOTAL / 64
#define NZERO   240         // 15360 padding rows / 64

typedef __attribute__((ext_vector_type(8))) short    bf16x8;
typedef __attribute__((ext_vector_type(4))) float    f32x4;
typedef __attribute__((ext_vector_type(4))) unsigned u32x4;

__device__ __forceinline__ unsigned short f2bf(float f) {
  unsigned u = __builtin_bit_cast(unsigned, f);
  u += 0x7fffu + ((u >> 16) & 1u);
  return (unsigned short)(u >> 16);
}

__device__ __forceinline__ unsigned cvtpk(float lo, float hi) {
  unsigned r;
  asm("v_cvt_pk_bf16_f32 %0, %1, %2" : "=v"(r) : "v"(lo), "v"(hi));
  return r;
}

// async global->LDS, 16B per lane; LDS dest = wave-uniform base + lane*16
__device__ __forceinline__ void gload16(const void* g, void* l) {
  __builtin_amdgcn_global_load_lds(
      (const __attribute__((address_space(1))) unsigned int*)g,
      (__attribute__((address_space(3))) unsigned int*)l,
      16, 0, 0);
}

// ---------------------------------------------------------------------------
// Kernel 1: W [768][256] f32 -> Wt_tiled bf16 in EXACT per-K-step LDS image
// order: element (kt, h, col, e) = bf16(W[kt*32 + h*8 + e][col]).
// GEMM staging of B is then a contiguous 16KB copy per K-step.
// ---------------------------------------------------------------------------
__global__ __launch_bounds__(256) void wt_tile(const float* __restrict__ W,
                                               unsigned short* __restrict__ Wt) {
  __shared__ float Wl[32][257];     // +1 pad
  const int kt  = blockIdx.x;       // 0..23
  const int tid = threadIdx.x;

#pragma unroll
  for (int i = 0; i < 8; ++i) {
    const int idx = i * 256 + tid;          // 0..2047 chunks of f32x4
    const int row = idx >> 6;
    const int c4  = idx & 63;
    f32x4 v = *(const f32x4*)(W + (size_t)(kt * 32 + row) * N_DIM + c4 * 4);
    Wl[row][c4 * 4 + 0] = v[0];
    Wl[row][c4 * 4 + 1] = v[1];
    Wl[row][c4 * 4 + 2] = v[2];
    Wl[row][c4 * 4 + 3] = v[3];
  }
  __syncthreads();

#pragma unroll
  for (int h = 0; h < 4; ++h) {
    bf16x8 ov;
#pragma unroll
    for (int e = 0; e < 8; ++e) ov[e] = (short)f2bf(Wl[h * 8 + e][tid]);
    *(bf16x8*)(Wt + (((size_t)kt * 4 + h) * 256 + tid) * 8) = ov;
  }
}

// ---------------------------------------------------------------------------
// Kernel 2: GEMM + scatter + fused padding zero-fill.
//   blocks [0, NGEMM):    BM=64 GEMM tile, 2-phase pipeline
//   blocks [NGEMM, +240): zero 64 padding rows each (write-only, overlaps)
//
// Round-8 change (LDS-BW was the limiter): A is reg-staged to BF16 before LDS
// -> halves A LDS read+write bytes and moves cvtpk out of the MFMA path.
//   A image (4KB/buf, bf16): slot16 = g*64 + (row ^ (2g)), g = k-octet 0..3.
//       stage (threads<256): row=t>>2, g=t&3; reads 8 consecutive f32
//       (coalesced: 4 threads cover one row's 128B), cvt_pk, one ds_write_b128.
//       write: 2-way banks (free). frag read: 16 lanes hit a permuted
//       contiguous 256B window -> conflict-free.
//   B image (16KB/buf): contiguous DMA copy from Wt_tiled (proven).
// 512 threads = 8 waves (2m x 4n); per-wave 32x64 tile (2x4 frags, acc 32).
// ---------------------------------------------------------------------------
__global__ __launch_bounds__(512, 4) void gemm_scatter(const float* __restrict__ A,
                                                       const unsigned short* __restrict__ Wt,
                                                       const float* __restrict__ bias,
                                                       float* __restrict__ out) {
  const int tid = threadIdx.x;

  // ---------------- fused zero-fill blocks ----------------
  if (blockIdx.x >= NGEMM) {
    const int z  = blockIdx.x - NGEMM;   // 0..239
    const int p0 = z * 64;               // global padding-row index
    int d = 0, c = 0;
    while (d < 15) {
      const int pad = 1920 - 128 * d;
      if (p0 < c + pad) break;
      c += pad; ++d;
    }
    const int len = 1024 + 128 * d;
    const size_t row0 = (size_t)d * MAXLEN + len + (p0 - c);
    float* dst = out + row0 * N_DIM;
    const f32x4 z4 = {0.f, 0.f, 0.f, 0.f};
#pragma unroll
    for (int j = 0; j < 8; ++j)
      *(f32x4*)(dst + (size_t)(j * 512 + tid) * 4) = z4;
    return;
  }

  // ---------------- GEMM blocks ----------------
  __shared__ f32x4 AbV[2][256];    // 2 x 4KB  (bf16 A image)
  __shared__ f32x4 BbV[2][1024];   // 2 x 16KB (bf16 B image)

  const int wid  = tid >> 6;
  const int lane = tid & 63;
  const int l15  = lane & 15;
  const int l4   = lane >> 4;
  const int wr   = wid >> 2;     // 0..1  (M half)
  const int wc   = wid & 3;      // 0..3  (N quarter)
  const int t0   = blockIdx.x * 64;

  // which doc does this tile live in (tiles never straddle docs)
  int off = 0, doc = 0;
  while (doc < 15) {
    const int len = 1024 + 128 * doc;
    if (t0 < off + len) break;
    off += len; ++doc;
  }
  const long tgt0 = (long)doc * MAXLEN + (t0 - off);

  // ---- A stage (threads < 256): row = t>>2, g = t&3 ----
  const int rowS = (tid & 255) >> 2;
  const int gS   = tid & 3;
  const float* pA = A + (size_t)(t0 + rowS) * K_DIM + gS * 8;
  const int awbyte = (gS * 64 + (rowS ^ (gS << 1))) * 16;   // XOR-permuted slot

  // ---- B DMA source (contiguous 16KB per K-step) ----
  const unsigned short* pB = Wt + (size_t)tid * 8;

  char* ldsA  = (char*)&AbV[0][0];
  char* ldsB  = (char*)&BbV[0][0];
  char* ldsBw = ldsB + wid * 1024;

  // ---- fragment read offsets ----
  const int arow  = wr * 32 + l15;
  const int aoff0 = l4 * 1024 + ((arow ^ (l4 << 1)) * 16);   // mf=0; mf=1 -> +256
  const int boff  = l4 * 4096 + (wc * 64 + l15) * 16;        // nf -> +nf*256

  f32x4 acc[2][4];
#pragma unroll
  for (int m = 0; m < 2; ++m)
#pragma unroll
    for (int n = 0; n < 4; ++n) acc[m][n] = f32x4{0.f, 0.f, 0.f, 0.f};

#define STAGE_B(buf, kt_)                                                \
  {                                                                      \
    gload16(pB + (size_t)(kt_) * 8192, ldsBw + (buf) * 16384);           \
    gload16(pB + (size_t)(kt_) * 8192 + 4096,                            \
            ldsBw + (buf) * 16384 + 8192);                               \
  }

#define WRITE_A(buf, La0, La1)                                           \
  {                                                                      \
    u32x4 u;                                                             \
    u[0] = cvtpk(La0[0], La0[1]); u[1] = cvtpk(La0[2], La0[3]);          \
    u[2] = cvtpk(La1[0], La1[1]); u[3] = cvtpk(La1[2], La1[3]);          \
    *(u32x4*)(ldsA + (buf) * 4096 + awbyte) = u;                         \
  }

#define COMPUTE(buf)                                                     \
  {                                                                      \
    const char* ab = ldsA + (buf) * 4096;                                \
    const char* bb = ldsB + (buf) * 16384 + boff;                        \
    bf16x8 bf0 = *(const bf16x8*)(bb);                                   \
    bf16x8 bf1 = *(const bf16x8*)(bb + 256);                             \
    bf16x8 bf2 = *(const bf16x8*)(bb + 512);                             \
    bf16x8 bf3 = *(const bf16x8*)(bb + 768);                             \
    bf16x8 af0 = *(const bf16x8*)(ab + aoff0);                           \
    bf16x8 af1 = *(const bf16x8*)(ab + aoff0 + 256);                     \
    acc[0][0] = __builtin_amdgcn_mfma_f32_16x16x32_bf16(af0, bf0, acc[0][0], 0, 0, 0); \
    acc[0][1] = __builtin_amdgcn_mfma_f32_16x16x32_bf16(af0, bf1, acc[0][1], 0, 0, 0); \
    acc[0][2] = __builtin_amdgcn_mfma_f32_16x16x32_bf16(af0, bf2, acc[0][2], 0, 0, 0); \
    acc[0][3] = __builtin_amdgcn_mfma_f32_16x16x32_bf16(af0, bf3, acc[0][3], 0, 0, 0); \
    acc[1][0] = __builtin_amdgcn_mfma_f32_16x16x32_bf16(af1, bf0, acc[1][0], 0, 0, 0); \
    acc[1][1] = __builtin_amdgcn_mfma_f32_16x16x32_bf16(af1, bf1, acc[1][1], 0, 0, 0); \
    acc[1][2] = __builtin_amdgcn_mfma_f32_16x16x32_bf16(af1, bf2, acc[1][2], 0, 0, 0); \
    acc[1][3] = __builtin_amdgcn_mfma_f32_16x16x32_bf16(af1, bf3, acc[1][3], 0, 0, 0); \
  }

  // prologue: stage tile 0 (A via regs, B via DMA), barrier
  if (tid < 256) {
    f32x4 La0 = *(const f32x4*)(pA);
    f32x4 La1 = *(const f32x4*)(pA + 4);
    WRITE_A(0, La0, La1)
  }
  STAGE_B(0, 0)
  __syncthreads();

  // main loop: issue A loads(t+1) early, B DMA(t+1), compute(t), write A(t+1)
#pragma unroll 1
  for (int t = 0; t < NKT - 1; ++t) {
    f32x4 La0, La1;
    if (tid < 256) {
      La0 = *(const f32x4*)(pA + (t + 1) * 32);
      La1 = *(const f32x4*)(pA + (t + 1) * 32 + 4);
    }
    STAGE_B((t + 1) & 1, t + 1)
    COMPUTE(t & 1)
    if (tid < 256) WRITE_A((t + 1) & 1, La0, La1)
    __syncthreads();
  }
  COMPUTE((NKT - 1) & 1)

  // epilogue: bias + scatter to padded rows
  float bc[4];
#pragma unroll
  for (int n = 0; n < 4; ++n) bc[n] = bias[wc * 64 + n * 16 + l15];

#pragma unroll
  for (int m = 0; m < 2; ++m)
#pragma unroll
    for (int n = 0; n < 4; ++n) {
      const size_t base = (size_t)(tgt0 + wr * 32 + m * 16 + l4 * 4) * N_DIM
                        + wc * 64 + n * 16 + l15;
#pragma unroll
      for (int j = 0; j < 4; ++j)
        out[base + (size_t)j * N_DIM] = acc[m][n][j] + bc[n];
    }
#undef STAGE_B
#undef WRITE_A
#undef COMPUTE
}

// ---------------------------------------------------------------------------
extern "C" void kernel_launch(void* const* d_in, const int* in_sizes, int n_in,
                              void* d_out, int out_size, void* d_ws, size_t ws_size,
                              hipStream_t stream) {
  const float* A    = (const float*)d_in[0];   // [31744, 768]
  const float* W    = (const float*)d_in[1];   // [768, 256]
  const float* bias = (const float*)d_in[2];   // [256]
  float* out = (float*)d_out;                  // [16, 2944, 256]
  unsigned short* Wt = (unsigned short*)d_ws;  // Wt_tiled bf16 [24][4][256][8]

  wt_tile<<<24, 256, 0, stream>>>(W, Wt);
  gemm_scatter<<<NGEMM + NZERO, 512, 0, stream>>>(A, Wt, bias, out);
}